// Round 1
// baseline (1203.902 us; speedup 1.0000x reference)
//
#include <hip/hip_runtime.h>

#define T_STEPS 1000
#define BATCH   256
#define NHID    200
#define BETA_C  0.85f
#define THR_C   1.0f

__launch_bounds__(256, 1)
__global__ void rsnn_kernel(const float* __restrict__ X,
                            const float* __restrict__ W1,
                            const float* __restrict__ b1,
                            const float* __restrict__ Wrec,
                            const float* __restrict__ brec,
                            const float* __restrict__ W2,
                            const float* __restrict__ b2,
                            float* __restrict__ out_cur2,
                            float* __restrict__ out_spk) {
#pragma clang fp contract(off)
    // WT[i*NHID + j] = Wrec[j*NHID + i]  (transposed: firing neuron i -> column read by thread j)
    __shared__ float        WT[NHID * NHID + 256];   // +256 pad so threads j>=200 read in-bounds garbage
    __shared__ unsigned int masks[2][8];             // double-buffered 256-bit spike masks
    __shared__ float        c2buf[2][4];             // per-wave partial sums for cur2

    const int tid  = threadIdx.x;
    const int b    = blockIdx.x;
    const int wave = tid >> 6;

    // --- stage Wrec transposed into LDS (coalesced global reads) ---
    for (int idx = tid; idx < NHID * NHID; idx += 256) {
        int j = idx / NHID;            // row of Wrec
        int n = idx - j * NHID;        // col of Wrec
        WT[n * NHID + j] = Wrec[idx];
    }
    for (int idx = NHID * NHID + tid; idx < NHID * NHID + 256; idx += 256) WT[idx] = 0.f;
    if (tid < 8) masks[0][tid] = 0u;   // F_{-1} = empty

    const int jc   = (tid < NHID) ? tid : (NHID - 1);
    const float w10 = W1[jc * 3 + 0], w11 = W1[jc * 3 + 1], w12 = W1[jc * 3 + 2];
    const float b1j = b1[jc], brecj = brec[jc], w2j = W2[jc];
    const float b2v = b2[0];

    float mem  = 0.f;
    float spkf = 0.f;

    __syncthreads();

    const float* xp           = X + (size_t)b * 3;                 // + t*BATCH*3
    float*       spk_out_base = out_spk + (size_t)b * NHID + tid;  // + t*BATCH*NHID

    for (int t = 0; t < T_STEPS; ++t) {
        const int s = t & 1;

        // ---- store previous step's outputs (issued early; ack hides under rec loop) ----
        if (t > 0) {
            if (tid < NHID)
                spk_out_base[(size_t)(t - 1) * BATCH * NHID] = spkf;
            if (tid == 0)
                out_cur2[(size_t)(t - 1) * BATCH + b] =
                    ((c2buf[s][0] + c2buf[s][1]) + (c2buf[s][2] + c2buf[s][3])) + b2v;
        }

        // ---- input current (uniform address; latency hidden under rec loop) ----
        const float x0 = xp[(size_t)t * BATCH * 3 + 0];
        const float x1 = xp[(size_t)t * BATCH * 3 + 1];
        const float x2 = xp[(size_t)t * BATCH * 3 + 2];

        // ---- recurrent input: in-order sparse sum over firing neurons ----
        float rec = 0.f;
        for (int w = 0; w < 7; ++w) {
            unsigned m = masks[s][w];
            const float* wt = WT + w * 32 * NHID + tid;
            while (m) {
                int bit = __builtin_ctz(m);
                m &= m - 1;
                rec += wt[bit * NHID];   // exact: equals dense in-order fma over k
            }
        }

        // ---- membrane update (replicates numpy op/rounding order exactly) ----
        float cur1    = fmaf(x2, w12, fmaf(x1, w11, x0 * w10)) + b1j;
        float base    = ((BETA_C * mem + cur1) + rec) + brecj;
        float mem_new = (mem > THR_C) ? 0.f : base;     // zero reset from OLD mem
        float sp      = (mem_new > THR_C) ? 1.f : 0.f;
        mem  = mem_new;
        spkf = sp;

        // ---- publish spike mask for next step (double-buffered) ----
        unsigned long long mk = __ballot((tid < NHID) && (sp > 0.5f));
        if ((tid & 63) == 0) {
            masks[s ^ 1][2 * wave]     = (unsigned)(mk & 0xffffffffull);
            masks[s ^ 1][2 * wave + 1] = (unsigned)(mk >> 32);
        }

        // ---- cur2 partial (terminal output: tree-reduce rounding OK) ----
        float v = (tid < NHID) ? sp * w2j : 0.f;
        for (int o = 32; o >= 1; o >>= 1) v += __shfl_xor(v, o);
        if ((tid & 63) == 0) c2buf[s ^ 1][wave] = v;

        __syncthreads();
    }

    // ---- epilogue: final step's outputs ----
    {
        const int s = T_STEPS & 1;  // slot holding step T-1 results
        if (tid < NHID)
            spk_out_base[(size_t)(T_STEPS - 1) * BATCH * NHID] = spkf;
        if (tid == 0)
            out_cur2[(size_t)(T_STEPS - 1) * BATCH + b] =
                ((c2buf[s][0] + c2buf[s][1]) + (c2buf[s][2] + c2buf[s][3])) + b2v;
    }
}

extern "C" void kernel_launch(void* const* d_in, const int* in_sizes, int n_in,
                              void* d_out, int out_size, void* d_ws, size_t ws_size,
                              hipStream_t stream) {
    const float* X    = (const float*)d_in[0];
    const float* W1   = (const float*)d_in[1];
    const float* b1   = (const float*)d_in[2];
    const float* Wrec = (const float*)d_in[3];
    const float* brec = (const float*)d_in[4];
    const float* W2   = (const float*)d_in[5];
    const float* b2   = (const float*)d_in[6];

    float* out_cur2 = (float*)d_out;                       // [T,B,1] flat
    float* out_spk  = (float*)d_out + (size_t)T_STEPS * BATCH;  // [T,B,200] flat

    rsnn_kernel<<<BATCH, 256, 0, stream>>>(X, W1, b1, Wrec, brec, W2, b2,
                                           out_cur2, out_spk);
}

// Round 2
// 967.049 us; speedup vs baseline: 1.2449x; 1.2449x over previous
//
#include <hip/hip_runtime.h>

#define T_STEPS 1000
#define BATCH   256
#define NHID    200
#define ROWF    204      // floats per LDS row (816 B): 200 weights + W2[i] + 3 pad
#define BETA_C  0.85f
#define THR_C   1.0f

// Row i of WT2 holds, at float offset l*4+k (l<50,k<4): Wrec[(l+50k)][i],
// and at offset 200: W2[i]. Lane l does ONE ds_read_b128 per firing neuron i,
// getting the 4 weights for its output neurons {l, l+50, l+100, l+150}.
// Lane 50's b128 starts at offset 200 -> v0.x = W2[i], so its rec0
// accumulates cur2 for free, in ascending-i order.

__launch_bounds__(64, 1)
__global__ void rsnn_kernel(const float* __restrict__ X,
                            const float* __restrict__ W1,
                            const float* __restrict__ b1,
                            const float* __restrict__ Wrec,
                            const float* __restrict__ brec,
                            const float* __restrict__ W2,
                            const float* __restrict__ b2,
                            float* __restrict__ out_cur2,
                            float* __restrict__ out_spk) {
#pragma clang fp contract(off)
    __shared__ float WT2[40852];   // 199*204 + 63*4 + 4 = 40852 floats = 163,408 B

    const int l = threadIdx.x;
    const int b = blockIdx.x;

    // ---- stage Wrec (permuted transpose) + W2 into LDS ----
    for (int idx = l; idx < NHID * NHID; idx += 64) {
        int r  = idx / NHID;            // Wrec row  (output neuron)
        int i  = idx - r * NHID;        // Wrec col  (source neuron)
        int lo = r % 50, k = r / 50;
        WT2[i * ROWF + lo * 4 + k] = Wrec[idx];
    }
    for (int i = l; i < NHID; i += 64) WT2[i * ROWF + 200] = W2[i];
    __syncthreads();

    const int lc = (l < 50) ? l : 49;
    float w1r[4][3], b1r[4], brr[4];
#pragma unroll
    for (int k = 0; k < 4; ++k) {
        int i = lc + 50 * k;
        w1r[k][0] = W1[i * 3 + 0];
        w1r[k][1] = W1[i * 3 + 1];
        w1r[k][2] = W1[i * 3 + 2];
        b1r[k] = b1[i];
        brr[k] = brec[i];
    }
    const float b2v = b2[0];

    float mem0 = 0.f, mem1 = 0.f, mem2 = 0.f, mem3 = 0.f;
    unsigned long long bm0 = 0, bm1 = 0, bm2 = 0, bm3 = 0;

    const float* xp = X + (size_t)b * 3;
    float x0 = xp[0], x1 = xp[1], x2 = xp[2];

    float*       spk_base = out_spk + (size_t)b * NHID + lc;
    const float* ldsrow   = WT2 + (size_t)l * 4;

#define REC_WORD(MASK, BASE)                                                          \
    {                                                                                 \
        unsigned long long m = (MASK);                                                \
        while (m) {                                                                   \
            int i0 = __builtin_ctzll(m); m &= m - 1;                                  \
            bool h1 = m != 0; int i1 = h1 ? __builtin_ctzll(m) : i0; if (h1) m &= m - 1; \
            bool h2 = m != 0; int i2 = h2 ? __builtin_ctzll(m) : i0; if (h2) m &= m - 1; \
            bool h3 = m != 0; int i3 = h3 ? __builtin_ctzll(m) : i0; if (h3) m &= m - 1; \
            const float4 v0 = *(const float4*)(ldsrow + (i0 + (BASE)) * ROWF);        \
            const float4 v1 = *(const float4*)(ldsrow + (i1 + (BASE)) * ROWF);        \
            const float4 v2 = *(const float4*)(ldsrow + (i2 + (BASE)) * ROWF);        \
            const float4 v3 = *(const float4*)(ldsrow + (i3 + (BASE)) * ROWF);        \
            rec0 += v0.x; rec1 += v0.y; rec2 += v0.z; rec3 += v0.w;                   \
            if (h1) { rec0 += v1.x; rec1 += v1.y; rec2 += v1.z; rec3 += v1.w; }       \
            if (h2) { rec0 += v2.x; rec1 += v2.y; rec2 += v2.z; rec3 += v2.w; }       \
            if (h3) { rec0 += v3.x; rec1 += v3.y; rec2 += v3.z; rec3 += v3.w; }       \
        }                                                                             \
    }

    for (int t = 0; t < T_STEPS; ++t) {
        // prefetch next step's input (used one iteration later)
        int   tn  = (t + 1 < T_STEPS) ? t + 1 : t;
        float nx0 = xp[(size_t)tn * BATCH * 3 + 0];
        float nx1 = xp[(size_t)tn * BATCH * 3 + 1];
        float nx2 = xp[(size_t)tn * BATCH * 3 + 2];

        // ---- sparse recurrent input from previous step's spikes ----
        float rec0 = 0.f, rec1 = 0.f, rec2 = 0.f, rec3 = 0.f;
        REC_WORD(bm0, 0)
        REC_WORD(bm1, 50)
        REC_WORD(bm2, 100)
        REC_WORD(bm3, 150)

        // lane 50's rec0 = sum of W2 over firing set of step t-1 = cur2_{t-1}
        if (t > 0 && l == 50)
            out_cur2[(size_t)(t - 1) * BATCH + b] = rec0 + b2v;

        // ---- membrane update (numpy op/rounding order preserved) ----
        float c0 = fmaf(x2, w1r[0][2], fmaf(x1, w1r[0][1], x0 * w1r[0][0])) + b1r[0];
        float c1 = fmaf(x2, w1r[1][2], fmaf(x1, w1r[1][1], x0 * w1r[1][0])) + b1r[1];
        float c2 = fmaf(x2, w1r[2][2], fmaf(x1, w1r[2][1], x0 * w1r[2][0])) + b1r[2];
        float c3 = fmaf(x2, w1r[3][2], fmaf(x1, w1r[3][1], x0 * w1r[3][0])) + b1r[3];

        float ba0 = ((BETA_C * mem0 + c0) + rec0) + brr[0];
        float ba1 = ((BETA_C * mem1 + c1) + rec1) + brr[1];
        float ba2 = ((BETA_C * mem2 + c2) + rec2) + brr[2];
        float ba3 = ((BETA_C * mem3 + c3) + rec3) + brr[3];

        float nm0 = (mem0 > THR_C) ? 0.f : ba0;
        float nm1 = (mem1 > THR_C) ? 0.f : ba1;
        float nm2 = (mem2 > THR_C) ? 0.f : ba2;
        float nm3 = (mem3 > THR_C) ? 0.f : ba3;

        float sp0 = (nm0 > THR_C) ? 1.f : 0.f;
        float sp1 = (nm1 > THR_C) ? 1.f : 0.f;
        float sp2 = (nm2 > THR_C) ? 1.f : 0.f;
        float sp3 = (nm3 > THR_C) ? 1.f : 0.f;

        mem0 = nm0; mem1 = nm1; mem2 = nm2; mem3 = nm3;

        // ---- record spikes (fire-and-forget stores, no barrier anywhere) ----
        if (l < 50) {
            float* sb = spk_base + (size_t)t * BATCH * NHID;
            sb[0]   = sp0;
            sb[50]  = sp1;
            sb[100] = sp2;
            sb[150] = sp3;
        }

        // ---- publish wave-uniform spike masks for next step ----
        bm0 = __ballot((l < 50) && (sp0 > 0.5f));
        bm1 = __ballot((l < 50) && (sp1 > 0.5f));
        bm2 = __ballot((l < 50) && (sp2 > 0.5f));
        bm3 = __ballot((l < 50) && (sp3 > 0.5f));

        x0 = nx0; x1 = nx1; x2 = nx2;
    }

    // ---- epilogue: cur2_{T-1} from final spike masks (same ascending order) ----
    {
        float c2f = 0.f;
        unsigned long long ms0 = bm0, ms1 = bm1, ms2 = bm2, ms3 = bm3;
#define C2_WORD(M, BASE)                                             \
        {                                                            \
            unsigned long long m = (M);                              \
            while (m) {                                              \
                int i = __builtin_ctzll(m) + (BASE); m &= m - 1;     \
                c2f += WT2[i * ROWF + 200];                          \
            }                                                        \
        }
        C2_WORD(ms0, 0) C2_WORD(ms1, 50) C2_WORD(ms2, 100) C2_WORD(ms3, 150)
        if (l == 50)
            out_cur2[(size_t)(T_STEPS - 1) * BATCH + b] = c2f + b2v;
#undef C2_WORD
    }
#undef REC_WORD
}

extern "C" void kernel_launch(void* const* d_in, const int* in_sizes, int n_in,
                              void* d_out, int out_size, void* d_ws, size_t ws_size,
                              hipStream_t stream) {
    const float* X    = (const float*)d_in[0];
    const float* W1   = (const float*)d_in[1];
    const float* b1   = (const float*)d_in[2];
    const float* Wrec = (const float*)d_in[3];
    const float* brec = (const float*)d_in[4];
    const float* W2   = (const float*)d_in[5];
    const float* b2   = (const float*)d_in[6];

    float* out_cur2 = (float*)d_out;                            // [T,B,1] flat
    float* out_spk  = (float*)d_out + (size_t)T_STEPS * BATCH;  // [T,B,200] flat

    rsnn_kernel<<<BATCH, 64, 0, stream>>>(X, W1, b1, Wrec, brec, W2, b2,
                                          out_cur2, out_spk);
}